// Round 1
// baseline (993.528 us; speedup 1.0000x reference)
//
#include <hip/hip_runtime.h>
#include <hip/hip_bf16.h>

// Problem constants
#define F 1024
#define N 64
#define C 256
#define HID 1024
#define NH 8
#define D 128

using bf16x8 = __attribute__((ext_vector_type(8))) short;
using u16x8  = __attribute__((ext_vector_type(8))) unsigned short;
using f32x4  = __attribute__((ext_vector_type(4))) float;

__device__ __forceinline__ unsigned short f2b(float f) {
    union { float f; unsigned u; } v; v.f = f;
    unsigned u = v.u;
    unsigned r = (u + 0x7fffu + ((u >> 16) & 1u)) >> 16;  // RNE
    return (unsigned short)r;
}
__device__ __forceinline__ float b2f(unsigned short h) {
    union { unsigned u; float f; } v; v.u = ((unsigned)h) << 16;
    return v.f;
}

// ---- Kernel 0a: x (f,n,c) fp32 -> bf16 flat copy -------------------------
__global__ void k_conv_x(const float* __restrict__ x, unsigned short* __restrict__ xb) {
    int i = (blockIdx.x * 256 + threadIdx.x) * 8;
    float4 a = *(const float4*)(x + i);
    float4 b = *(const float4*)(x + i + 4);
    u16x8 o;
    o[0] = f2b(a.x); o[1] = f2b(a.y); o[2] = f2b(a.z); o[3] = f2b(a.w);
    o[4] = f2b(b.x); o[5] = f2b(b.y); o[6] = f2b(b.z); o[7] = f2b(b.w);
    *(u16x8*)(xb + i) = o;
}

// ---- Kernel 0b: W (c,hid) fp32 -> Wt[w][hid][c] bf16 (transposed) --------
__global__ void k_conv_w(const float* __restrict__ Wq, const float* __restrict__ Wk,
                         const float* __restrict__ Wv, unsigned short* __restrict__ Wt) {
    int w = blockIdx.z;
    const float* W = (w == 0) ? Wq : ((w == 1) ? Wk : Wv);
    unsigned short* O = Wt + w * (HID * C);
    int n0 = blockIdx.x * 64, k0 = blockIdx.y * 64;
    __shared__ float t[64][65];
    int tx = threadIdx.x & 63, ty = threadIdx.x >> 6;
#pragma unroll
    for (int i = 0; i < 16; i++) {
        int kl = ty + i * 4;
        t[kl][tx] = W[(k0 + kl) * HID + n0 + tx];
    }
    __syncthreads();
#pragma unroll
    for (int i = 0; i < 16; i++) {
        int nl = ty + i * 4;
        O[(n0 + nl) * C + k0 + tx] = f2b(t[tx][nl]);
    }
}

// ---- Kernel 1: QKV projection + bias + elu+1, layout-aware stores --------
// Q  stored (n,h,f,d)   : Q[(ni*8+h)*F*D + fi*D + dd]
// Kt,Vt stored (n,h,d,f): T[(ni*8+h)*D*F + dd*F + fi]
__global__ __launch_bounds__(256, 2) void k_qkv(
    const unsigned short* __restrict__ xb, const unsigned short* __restrict__ Wt,
    const float* __restrict__ bq, const float* __restrict__ bk, const float* __restrict__ bv,
    unsigned short* __restrict__ Q, unsigned short* __restrict__ Kt,
    unsigned short* __restrict__ Vt) {
    const int mt = blockIdx.x;               // 0..511 : (ni, fi-tile)
    const int ni = mt >> 3, fi0 = (mt & 7) << 7;
    const int u = blockIdx.y;                // 0..23 : (out_id, h)
    const int out_id = u >> 3, h = u & 7;
    const int tid = threadIdx.x, lane = tid & 63, w = tid >> 6;
    const int quad = lane >> 4, l15 = lane & 15;

    const unsigned short* Wp = Wt + out_id * (HID * C) + (h * D) * C;
    const float* bias = ((out_id == 0) ? bq : ((out_id == 1) ? bk : bv)) + h * D;

    f32x4 acc[2][8];
#pragma unroll
    for (int a = 0; a < 2; a++)
#pragma unroll
        for (int b = 0; b < 8; b++) acc[a][b] = (f32x4)0.f;

    if (out_id == 0) {
        // C[fi][dd] = sum_k x[fi][k] * Wt[dd][k]
#pragma unroll
        for (int ks = 0; ks < C; ks += 32) {
            bf16x8 af[2], bfr[8];
#pragma unroll
            for (int mb = 0; mb < 2; mb++) {
                int fi = fi0 + w * 32 + mb * 16 + l15;
                af[mb] = *(const bf16x8*)(xb + (fi * N + ni) * C + ks + quad * 8);
            }
#pragma unroll
            for (int nb = 0; nb < 8; nb++) {
                int dd = nb * 16 + l15;
                bfr[nb] = *(const bf16x8*)(Wp + dd * C + ks + quad * 8);
            }
#pragma unroll
            for (int mb = 0; mb < 2; mb++)
#pragma unroll
                for (int nb = 0; nb < 8; nb++)
                    acc[mb][nb] = __builtin_amdgcn_mfma_f32_16x16x32_bf16(
                        af[mb], bfr[nb], acc[mb][nb], 0, 0, 0);
        }
        float bcol[8];
#pragma unroll
        for (int nb = 0; nb < 8; nb++) bcol[nb] = bias[nb * 16 + l15];
        unsigned short* Qp = Q + (ni * NH + h) * (F * D);
#pragma unroll
        for (int mb = 0; mb < 2; mb++)
#pragma unroll
            for (int r = 0; r < 4; r++) {
                int fi = fi0 + w * 32 + mb * 16 + quad * 4 + r;
#pragma unroll
                for (int nb = 0; nb < 8; nb++) {
                    int dd = nb * 16 + l15;
                    float v = acc[mb][nb][r] + bcol[nb];
                    v = (v > 0.f) ? (v + 1.f) : __expf(v);
                    Qp[fi * D + dd] = f2b(v);
                }
            }
    } else {
        // Swapped operands: C[dd][fi] = sum_k Wt[dd][k] * x[fi][k]
#pragma unroll
        for (int ks = 0; ks < C; ks += 32) {
            bf16x8 af[2], bfr[8];
#pragma unroll
            for (int mb = 0; mb < 2; mb++) {
                int dd = w * 32 + mb * 16 + l15;
                af[mb] = *(const bf16x8*)(Wp + dd * C + ks + quad * 8);
            }
#pragma unroll
            for (int nb = 0; nb < 8; nb++) {
                int fi = fi0 + nb * 16 + l15;
                bfr[nb] = *(const bf16x8*)(xb + (fi * N + ni) * C + ks + quad * 8);
            }
#pragma unroll
            for (int mb = 0; mb < 2; mb++)
#pragma unroll
                for (int nb = 0; nb < 8; nb++)
                    acc[mb][nb] = __builtin_amdgcn_mfma_f32_16x16x32_bf16(
                        af[mb], bfr[nb], acc[mb][nb], 0, 0, 0);
        }
        float brow[2][4];
#pragma unroll
        for (int mb = 0; mb < 2; mb++)
#pragma unroll
            for (int r = 0; r < 4; r++)
                brow[mb][r] = bias[w * 32 + mb * 16 + quad * 4 + r];
        unsigned short* Tp =
            ((out_id == 1) ? Kt : Vt) + (ni * NH + h) * (D * F);
        const bool isk = (out_id == 1);
#pragma unroll
        for (int mb = 0; mb < 2; mb++)
#pragma unroll
            for (int r = 0; r < 4; r++) {
                int dd = w * 32 + mb * 16 + quad * 4 + r;
#pragma unroll
                for (int nb = 0; nb < 8; nb++) {
                    int fi = fi0 + nb * 16 + l15;
                    float v = acc[mb][nb][r] + brow[mb][r];
                    if (isk) v = (v > 0.f) ? (v + 1.f) : __expf(v);
                    Tp[dd * F + fi] = f2b(v);
                }
            }
    }
}

// ---- Kernel 2: per (n,h): KV[m][d] = sum_s Vt[m][s]*Kt[d][s]; Ksum[d] ----
__global__ __launch_bounds__(256, 2) void k_kv(
    const unsigned short* __restrict__ Kt, const unsigned short* __restrict__ Vt,
    unsigned short* __restrict__ KV, float* __restrict__ Ksum) {
    __shared__ float sred[256];
    const int b = blockIdx.x;  // n*8+h
    const unsigned short* Kp = Kt + b * (D * F);
    const unsigned short* Vp = Vt + b * (D * F);
    const int tid = threadIdx.x, lane = tid & 63, w = tid >> 6;
    const int quad = lane >> 4, l15 = lane & 15;

    // Ksum: 2 threads per d-row
    {
        int d = tid >> 1, half = tid & 1;
        const unsigned short* row = Kp + d * F + half * 512;
        float s = 0.f;
        for (int i = 0; i < 512; i += 8) {
            u16x8 v = *(const u16x8*)(row + i);
#pragma unroll
            for (int j = 0; j < 8; j++) s += b2f(v[j]);
        }
        sred[tid] = s;
        __syncthreads();
        if (tid < 128) Ksum[b * D + tid] = sred[2 * tid] + sred[2 * tid + 1];
    }

    f32x4 acc[2][8];
#pragma unroll
    for (int a = 0; a < 2; a++)
#pragma unroll
        for (int c = 0; c < 8; c++) acc[a][c] = (f32x4)0.f;

    for (int s0 = 0; s0 < F; s0 += 32) {
        bf16x8 af[2], bfr[8];
#pragma unroll
        for (int mb = 0; mb < 2; mb++) {
            int m = w * 32 + mb * 16 + l15;
            af[mb] = *(const bf16x8*)(Vp + m * F + s0 + quad * 8);
        }
#pragma unroll
        for (int nb = 0; nb < 8; nb++) {
            int d = nb * 16 + l15;
            bfr[nb] = *(const bf16x8*)(Kp + d * F + s0 + quad * 8);
        }
#pragma unroll
        for (int mb = 0; mb < 2; mb++)
#pragma unroll
            for (int nb = 0; nb < 8; nb++)
                acc[mb][nb] = __builtin_amdgcn_mfma_f32_16x16x32_bf16(
                    af[mb], bfr[nb], acc[mb][nb], 0, 0, 0);
    }
    unsigned short* KVp = KV + b * (D * D);
#pragma unroll
    for (int mb = 0; mb < 2; mb++)
#pragma unroll
        for (int r = 0; r < 4; r++) {
            int m = w * 32 + mb * 16 + quad * 4 + r;
#pragma unroll
            for (int nb = 0; nb < 8; nb++) {
                int d = nb * 16 + l15;
                KVp[m * D + d] = f2b(acc[mb][nb][r]);
            }
        }
}

// ---- Kernel 3: Z + out GEMM ----------------------------------------------
__global__ __launch_bounds__(256, 2) void k_out(
    const unsigned short* __restrict__ Q, const unsigned short* __restrict__ KV,
    const float* __restrict__ Ksum, float* __restrict__ out) {
    __shared__ float Kss[D];
    __shared__ float Zs[128];
    const int b = blockIdx.x, lt = blockIdx.y;
    const int ni = b >> 3, h = b & 7;
    const int l0 = lt * 128;
    const unsigned short* Qp = Q + b * (F * D) + l0 * D;
    const unsigned short* KVp = KV + b * (D * D);
    const int tid = threadIdx.x, lane = tid & 63, w = tid >> 6;
    const int quad = lane >> 4, l15 = lane & 15;

    if (tid < 128) Kss[tid] = Ksum[b * D + tid];
    __syncthreads();
    if (tid < 128) {
        const unsigned short* qr = Qp + tid * D;
        float s = 0.f;
#pragma unroll
        for (int i = 0; i < D; i += 8) {
            u16x8 v = *(const u16x8*)(qr + i);
#pragma unroll
            for (int j = 0; j < 8; j++) s += b2f(v[j]) * Kss[i + j];
        }
        Zs[tid] = 1.f / (s + 1e-6f);
    }
    __syncthreads();

    f32x4 acc[2][8];
#pragma unroll
    for (int a = 0; a < 2; a++)
#pragma unroll
        for (int c = 0; c < 8; c++) acc[a][c] = (f32x4)0.f;

#pragma unroll
    for (int k0 = 0; k0 < D; k0 += 32) {
        bf16x8 af[2], bfr[8];
#pragma unroll
        for (int mb = 0; mb < 2; mb++) {
            int ll = w * 32 + mb * 16 + l15;
            af[mb] = *(const bf16x8*)(Qp + ll * D + k0 + quad * 8);
        }
#pragma unroll
        for (int nb = 0; nb < 8; nb++) {
            int m = nb * 16 + l15;
            bfr[nb] = *(const bf16x8*)(KVp + m * D + k0 + quad * 8);
        }
#pragma unroll
        for (int mb = 0; mb < 2; mb++)
#pragma unroll
            for (int nb = 0; nb < 8; nb++)
                acc[mb][nb] = __builtin_amdgcn_mfma_f32_16x16x32_bf16(
                    af[mb], bfr[nb], acc[mb][nb], 0, 0, 0);
    }

#pragma unroll
    for (int mb = 0; mb < 2; mb++)
#pragma unroll
        for (int r = 0; r < 4; r++) {
            int ll = w * 32 + mb * 16 + quad * 4 + r;
            float z = Zs[ll];
            int l = l0 + ll;
            float* op = out + (l * N + ni) * HID + h * D;
#pragma unroll
            for (int nb = 0; nb < 8; nb++) {
                int m = nb * 16 + l15;
                op[m] = acc[mb][nb][r] * z;
            }
        }
}

// ---- launch --------------------------------------------------------------
// ws layout (bytes):
//   xb   @ 0          : 33,554,432  (16M bf16)
//   Wt   @ 33554432   :  1,572,864  (3*1024*256 bf16, transposed)
//   Q    @ 35127296   : 134,217,728 ((n,h,f,d) bf16)
//   Kt   @ 169345024  : 134,217,728 ((n,h,d,f) bf16)
//   Vt   @ 303562752  : 134,217,728 ((n,h,d,f) bf16)
//   KV   @ 437780480  :  16,777,216 ((n,h,m,d) bf16)
//   Ksum @ 454557696  :     262,144 ((n,h,d) fp32)
// total ~434 MB
extern "C" void kernel_launch(void* const* d_in, const int* in_sizes, int n_in,
                              void* d_out, int out_size, void* d_ws, size_t ws_size,
                              hipStream_t stream) {
    const float* x  = (const float*)d_in[0];
    const float* Wq = (const float*)d_in[1];
    const float* bq = (const float*)d_in[2];
    const float* Wk = (const float*)d_in[3];
    const float* bk = (const float*)d_in[4];
    const float* Wv = (const float*)d_in[5];
    const float* bv = (const float*)d_in[6];
    float* out = (float*)d_out;
    char* ws = (char*)d_ws;

    unsigned short* xb   = (unsigned short*)(ws);
    unsigned short* Wt   = (unsigned short*)(ws + 33554432);
    unsigned short* Qb   = (unsigned short*)(ws + 35127296);
    unsigned short* Ktb  = (unsigned short*)(ws + 169345024);
    unsigned short* Vtb  = (unsigned short*)(ws + 303562752);
    unsigned short* KVb  = (unsigned short*)(ws + 437780480);
    float*          Ksum = (float*)(ws + 454557696);

    k_conv_x<<<8192, 256, 0, stream>>>(x, xb);
    k_conv_w<<<dim3(16, 4, 3), 256, 0, stream>>>(Wq, Wk, Wv, Wt);
    k_qkv<<<dim3(512, 24), 256, 0, stream>>>(xb, Wt, bq, bk, bv, Qb, Ktb, Vtb);
    k_kv<<<512, 256, 0, stream>>>(Ktb, Vtb, KVb, Ksum);
    k_out<<<dim3(512, 8), 256, 0, stream>>>(Qb, KVb, Ksum, out);
}

// Round 2
// 717.606 us; speedup vs baseline: 1.3845x; 1.3845x over previous
//
#include <hip/hip_runtime.h>
#include <hip/hip_bf16.h>

// Problem constants
#define F 1024
#define N 64
#define C 256
#define HID 1024
#define NH 8
#define D 128

using bf16x8 = __attribute__((ext_vector_type(8))) short;
using u16x8  = __attribute__((ext_vector_type(8))) unsigned short;
using u16x4  = __attribute__((ext_vector_type(4))) unsigned short;
using f32x4  = __attribute__((ext_vector_type(4))) float;

__device__ __forceinline__ unsigned short f2b(float f) {
    union { float f; unsigned u; } v; v.f = f;
    unsigned u = v.u;
    unsigned r = (u + 0x7fffu + ((u >> 16) & 1u)) >> 16;  // RNE
    return (unsigned short)r;
}
__device__ __forceinline__ float b2f(unsigned short h) {
    union { unsigned u; float f; } v; v.u = ((unsigned)h) << 16;
    return v.f;
}

__device__ __forceinline__ void load_lds16(const unsigned short* g, unsigned short* l) {
    __builtin_amdgcn_global_load_lds(
        (const __attribute__((address_space(1))) void*)g,
        (__attribute__((address_space(3))) void*)l, 16, 0, 0);
}

// ---- Kernel 0a: x (f,n,c) fp32 -> xt (n,f,c) bf16 ------------------------
// one wave per row; read 16B/lane, write 8B/lane, both coalesced
__global__ void k_conv_x(const float* __restrict__ x, unsigned short* __restrict__ xt) {
    int row = blockIdx.x * 4 + (threadIdx.x >> 6);  // input row index over (f,n)
    int lane = threadIdx.x & 63;
    int fi = row >> 6, ni = row & 63;
    float4 a = *(const float4*)(x + row * C + lane * 4);
    u16x4 o;
    o[0] = f2b(a.x); o[1] = f2b(a.y); o[2] = f2b(a.z); o[3] = f2b(a.w);
    *(u16x4*)(xt + (ni * F + fi) * C + lane * 4) = o;
}

// ---- Kernel 0b: W (c,hid) fp32 -> Wt[w][hid][c] bf16 (transposed) --------
__global__ void k_conv_w(const float* __restrict__ Wq, const float* __restrict__ Wk,
                         const float* __restrict__ Wv, unsigned short* __restrict__ Wt) {
    int w = blockIdx.z;
    const float* W = (w == 0) ? Wq : ((w == 1) ? Wk : Wv);
    unsigned short* O = Wt + w * (HID * C);
    int n0 = blockIdx.x * 64, k0 = blockIdx.y * 64;
    __shared__ float t[64][65];
    int tx = threadIdx.x & 63, ty = threadIdx.x >> 6;
#pragma unroll
    for (int i = 0; i < 16; i++) {
        int kl = ty + i * 4;
        t[kl][tx] = W[(k0 + kl) * HID + n0 + tx];
    }
    __syncthreads();
#pragma unroll
    for (int i = 0; i < 16; i++) {
        int nl = ty + i * 4;
        O[(n0 + nl) * C + k0 + tx] = f2b(t[tx][nl]);
    }
}

// ---- Kernel 1: QKV projection, m97-style LDS-staged GEMM -----------------
// xt is (n,f,c): M-tile = 128 consecutive fi for one ni.
// Q  stored (n,h,f,d)   : Q[(ni*8+h)*F*D + fi*D + dd]     (Q-mode, C[fi][dd])
// Kt,Vt stored (n,h,d,f): T[(ni*8+h)*D*F + dd*F + fi]     (T-mode, C[dd][fi])
#define CT_PITCH 136
__global__ __launch_bounds__(256, 2) void k_qkv(
    const unsigned short* __restrict__ xt, const unsigned short* __restrict__ Wt,
    const float* __restrict__ bq, const float* __restrict__ bk, const float* __restrict__ bv,
    unsigned short* __restrict__ Q, unsigned short* __restrict__ Kt,
    unsigned short* __restrict__ Vt) {
    __shared__ unsigned short smem[128 * CT_PITCH];  // 34816 B; staging uses first 16 KB
    unsigned short* Xs = smem;           // 128 x 32
    unsigned short* Ws = smem + 4096;    // 128 x 32
    unsigned short* Ct = smem;           // 128 x CT_PITCH repack (after K-loop)

    const int mt = blockIdx.x;                 // 0..511
    const int ni = mt >> 3, fi0 = (mt & 7) << 7;
    const int u = blockIdx.y;                  // 0..23
    const int out_id = u >> 3, h = u & 7;
    const int tid = threadIdx.x, lane = tid & 63, w = tid >> 6;
    const int quad = lane >> 4, l15 = lane & 15;
    const int wm = w >> 1, wn = w & 1;

    const unsigned short* Ag = xt + (ni * F + fi0) * C;            // 128 rows, pitch C
    const unsigned short* Bg = Wt + out_id * (HID * C) + (h * D) * C;  // 128 rows, pitch C

    const int srow = lane >> 2;          // 0..15
    const int scol = (lane & 3) * 8;

    // Operand roles: Q-mode A=x rows (fi), B=W rows (dd); T-mode swapped.
    const unsigned short* As_f = (out_id == 0) ? Xs : Ws;
    const unsigned short* Bs_f = (out_id == 0) ? Ws : Xs;

    f32x4 acc[4][4];
#pragma unroll
    for (int i = 0; i < 4; i++)
#pragma unroll
        for (int j = 0; j < 4; j++) acc[i][j] = (f32x4)0.f;

#pragma unroll
    for (int ks = 0; ks < 8; ks++) {
        const int kof = ks * 32;
        // stage: wave w loads rows [w*32, w*32+32) of both tiles, 16B/lane
        const unsigned short* ga = Ag + (w * 32 + srow) * C + kof + scol;
        const unsigned short* gb = Bg + (w * 32 + srow) * C + kof + scol;
        load_lds16(ga,            Xs + (w * 32) * 32);
        load_lds16(ga + 16 * C,   Xs + (w * 32 + 16) * 32);
        load_lds16(gb,            Ws + (w * 32) * 32);
        load_lds16(gb + 16 * C,   Ws + (w * 32 + 16) * 32);
        __syncthreads();

        bf16x8 af[4], bfr[4];
#pragma unroll
        for (int mb = 0; mb < 4; mb++)
            af[mb] = *(const bf16x8*)(As_f + (wm * 64 + mb * 16 + l15) * 32 + quad * 8);
#pragma unroll
        for (int nb = 0; nb < 4; nb++)
            bfr[nb] = *(const bf16x8*)(Bs_f + (wn * 64 + nb * 16 + l15) * 32 + quad * 8);
#pragma unroll
        for (int mb = 0; mb < 4; mb++)
#pragma unroll
            for (int nb = 0; nb < 4; nb++)
                acc[mb][nb] = __builtin_amdgcn_mfma_f32_16x16x32_bf16(
                    af[mb], bfr[nb], acc[mb][nb], 0, 0, 0);
        __syncthreads();
    }

    const float* bias = ((out_id == 0) ? bq : ((out_id == 1) ? bk : bv)) + h * D;

    // epilogue: bias + activation, bf16 into LDS tile
    if (out_id == 0) {
        float bcol[4];
#pragma unroll
        for (int nb = 0; nb < 4; nb++) bcol[nb] = bias[wn * 64 + nb * 16 + l15];
#pragma unroll
        for (int mb = 0; mb < 4; mb++)
#pragma unroll
            for (int r = 0; r < 4; r++) {
                int row = wm * 64 + mb * 16 + quad * 4 + r;
#pragma unroll
                for (int nb = 0; nb < 4; nb++) {
                    int col = wn * 64 + nb * 16 + l15;
                    float v = acc[mb][nb][r] + bcol[nb];
                    v = (v > 0.f) ? (v + 1.f) : __expf(v);
                    Ct[row * CT_PITCH + col] = f2b(v);
                }
            }
    } else {
        const bool isk = (out_id == 1);
#pragma unroll
        for (int mb = 0; mb < 4; mb++)
#pragma unroll
            for (int r = 0; r < 4; r++) {
                int row = wm * 64 + mb * 16 + quad * 4 + r;  // dd
                float bb = bias[row];
#pragma unroll
                for (int nb = 0; nb < 4; nb++) {
                    int col = wn * 64 + nb * 16 + l15;       // fi local
                    float v = acc[mb][nb][r] + bb;
                    if (isk) v = (v > 0.f) ? (v + 1.f) : __expf(v);
                    Ct[row * CT_PITCH + col] = f2b(v);
                }
            }
    }
    __syncthreads();

    // store pass: 16B/lane coalesced
    if (out_id == 0) {
        unsigned short* Op = Q + (ni * NH + h) * (F * D) + fi0 * D;  // contiguous 32 KB
#pragma unroll
        for (int chunk = 0; chunk < 8; chunk++) {
            int idx = chunk * 256 + tid;
            int row = idx >> 4, col = (idx & 15) * 8;
            u16x8 v = *(const u16x8*)(Ct + row * CT_PITCH + col);
            *(u16x8*)(Op + row * D + col) = v;
        }
    } else {
        unsigned short* Op = ((out_id == 1) ? Kt : Vt) + (ni * NH + h) * (D * F) + fi0;
#pragma unroll
        for (int chunk = 0; chunk < 8; chunk++) {
            int idx = chunk * 256 + tid;
            int row = idx >> 4, col = (idx & 15) * 8;   // row=dd, col=fi local
            u16x8 v = *(const u16x8*)(Ct + row * CT_PITCH + col);
            *(u16x8*)(Op + row * F + col) = v;
        }
    }
}

// ---- Kernel 2: per (n,h): KV[m][d] = sum_s Vt[m][s]*Kt[d][s]; Ksum[d] ----
__global__ __launch_bounds__(256, 2) void k_kv(
    const unsigned short* __restrict__ Kt, const unsigned short* __restrict__ Vt,
    unsigned short* __restrict__ KV, float* __restrict__ Ksum) {
    __shared__ float sred[256];
    const int b = blockIdx.x;  // n*8+h
    const unsigned short* Kp = Kt + b * (D * F);
    const unsigned short* Vp = Vt + b * (D * F);
    const int tid = threadIdx.x, lane = tid & 63, w = tid >> 6;
    const int quad = lane >> 4, l15 = lane & 15;

    // Ksum: 2 threads per d-row
    {
        int d = tid >> 1, half = tid & 1;
        const unsigned short* row = Kp + d * F + half * 512;
        float s = 0.f;
        for (int i = 0; i < 512; i += 8) {
            u16x8 v = *(const u16x8*)(row + i);
#pragma unroll
            for (int j = 0; j < 8; j++) s += b2f(v[j]);
        }
        sred[tid] = s;
        __syncthreads();
        if (tid < 128) Ksum[b * D + tid] = sred[2 * tid] + sred[2 * tid + 1];
    }

    f32x4 acc[2][8];
#pragma unroll
    for (int a = 0; a < 2; a++)
#pragma unroll
        for (int c = 0; c < 8; c++) acc[a][c] = (f32x4)0.f;

    for (int s0 = 0; s0 < F; s0 += 32) {
        bf16x8 af[2], bfr[8];
#pragma unroll
        for (int mb = 0; mb < 2; mb++) {
            int m = w * 32 + mb * 16 + l15;
            af[mb] = *(const bf16x8*)(Vp + m * F + s0 + quad * 8);
        }
#pragma unroll
        for (int nb = 0; nb < 8; nb++) {
            int d = nb * 16 + l15;
            bfr[nb] = *(const bf16x8*)(Kp + d * F + s0 + quad * 8);
        }
#pragma unroll
        for (int mb = 0; mb < 2; mb++)
#pragma unroll
            for (int nb = 0; nb < 8; nb++)
                acc[mb][nb] = __builtin_amdgcn_mfma_f32_16x16x32_bf16(
                    af[mb], bfr[nb], acc[mb][nb], 0, 0, 0);
    }
    unsigned short* KVp = KV + b * (D * D);
#pragma unroll
    for (int mb = 0; mb < 2; mb++)
#pragma unroll
        for (int r = 0; r < 4; r++) {
            int m = w * 32 + mb * 16 + quad * 4 + r;
#pragma unroll
            for (int nb = 0; nb < 8; nb++) {
                int d = nb * 16 + l15;
                KVp[m * D + d] = f2b(acc[mb][nb][r]);
            }
        }
}

// ---- Kernel 3: Z + out GEMM (swapped: C[m][l] -> float4 stores) ----------
__global__ __launch_bounds__(256, 2) void k_out(
    const unsigned short* __restrict__ Q, const unsigned short* __restrict__ KV,
    const float* __restrict__ Ksum, float* __restrict__ out) {
    __shared__ float Kss[D];
    __shared__ float Zs[128];
    const int b = blockIdx.x, lt = blockIdx.y;
    const int ni = b >> 3, h = b & 7;
    const int l0 = lt * 128;
    const unsigned short* Qp = Q + b * (F * D) + l0 * D;
    const unsigned short* KVp = KV + b * (D * D);
    const int tid = threadIdx.x, lane = tid & 63, w = tid >> 6;
    const int quad = lane >> 4, l15 = lane & 15;
    const int wm = w >> 1, wn = w & 1;

    if (tid < 128) Kss[tid] = Ksum[b * D + tid];
    __syncthreads();
    if (tid < 128) {
        const unsigned short* qr = Qp + tid * D;
        float s = 0.f;
#pragma unroll
        for (int i = 0; i < D; i += 8) {
            u16x8 v = *(const u16x8*)(qr + i);
#pragma unroll
            for (int j = 0; j < 8; j++) s += b2f(v[j]) * Kss[i + j];
        }
        Zs[tid] = 1.f / (s + 1e-6f);
    }
    __syncthreads();

    // C[m][l] = sum_d KV[m][d] * Q[l][d]; wave tile 64m x 64l
    f32x4 acc[4][4];
#pragma unroll
    for (int a = 0; a < 4; a++)
#pragma unroll
        for (int c = 0; c < 4; c++) acc[a][c] = (f32x4)0.f;

#pragma unroll
    for (int k0 = 0; k0 < D; k0 += 32) {
        bf16x8 af[4], bfr[4];
#pragma unroll
        for (int mb = 0; mb < 4; mb++) {
            int m = wm * 64 + mb * 16 + l15;
            af[mb] = *(const bf16x8*)(KVp + m * D + k0 + quad * 8);
        }
#pragma unroll
        for (int nb = 0; nb < 4; nb++) {
            int l = wn * 64 + nb * 16 + l15;
            bfr[nb] = *(const bf16x8*)(Qp + l * D + k0 + quad * 8);
        }
#pragma unroll
        for (int mb = 0; mb < 4; mb++)
#pragma unroll
            for (int nb = 0; nb < 4; nb++)
                acc[mb][nb] = __builtin_amdgcn_mfma_f32_16x16x32_bf16(
                    af[mb], bfr[nb], acc[mb][nb], 0, 0, 0);
    }

#pragma unroll
    for (int nb = 0; nb < 4; nb++) {
        int l = wn * 64 + nb * 16 + l15;
        float z = Zs[l];
        float* op = out + ((l0 + l) * N + ni) * HID + h * D;
#pragma unroll
        for (int mb = 0; mb < 4; mb++) {
            int m0 = wm * 64 + mb * 16 + quad * 4;
            float4 vv;
            vv.x = acc[mb][nb][0] * z;
            vv.y = acc[mb][nb][1] * z;
            vv.z = acc[mb][nb][2] * z;
            vv.w = acc[mb][nb][3] * z;
            *(float4*)(op + m0) = vv;
        }
    }
}

// ---- launch --------------------------------------------------------------
// ws layout (bytes):
//   xt   @ 0          : 33,554,432  ((n,f,c) bf16)
//   Wt   @ 33554432   :  1,572,864  (3*1024*256 bf16, transposed)
//   Q    @ 35127296   : 134,217,728 ((n,h,f,d) bf16)
//   Kt   @ 169345024  : 134,217,728 ((n,h,d,f) bf16)
//   Vt   @ 303562752  : 134,217,728 ((n,h,d,f) bf16)
//   KV   @ 437780480  :  16,777,216 ((n,h,m,d) bf16)
//   Ksum @ 454557696  :     262,144 ((n,h,d) fp32)
extern "C" void kernel_launch(void* const* d_in, const int* in_sizes, int n_in,
                              void* d_out, int out_size, void* d_ws, size_t ws_size,
                              hipStream_t stream) {
    const float* x  = (const float*)d_in[0];
    const float* Wq = (const float*)d_in[1];
    const float* bq = (const float*)d_in[2];
    const float* Wk = (const float*)d_in[3];
    const float* bk = (const float*)d_in[4];
    const float* Wv = (const float*)d_in[5];
    const float* bv = (const float*)d_in[6];
    float* out = (float*)d_out;
    char* ws = (char*)d_ws;

    unsigned short* xt   = (unsigned short*)(ws);
    unsigned short* Wt   = (unsigned short*)(ws + 33554432);
    unsigned short* Qb   = (unsigned short*)(ws + 35127296);
    unsigned short* Ktb  = (unsigned short*)(ws + 169345024);
    unsigned short* Vtb  = (unsigned short*)(ws + 303562752);
    unsigned short* KVb  = (unsigned short*)(ws + 437780480);
    float*          Ksum = (float*)(ws + 454557696);

    k_conv_x<<<16384, 256, 0, stream>>>(x, xt);
    k_conv_w<<<dim3(16, 4, 3), 256, 0, stream>>>(Wq, Wk, Wv, Wt);
    k_qkv<<<dim3(512, 24), 256, 0, stream>>>(xt, Wt, bq, bk, bv, Qb, Ktb, Vtb);
    k_kv<<<512, 256, 0, stream>>>(Ktb, Vtb, KVb, Ksum);
    k_out<<<dim3(512, 8), 256, 0, stream>>>(Qb, KVb, Ksum, out);
}